// Round 11
// baseline (876.504 us; speedup 1.0000x reference)
//
#include <hip/hip_runtime.h>
#include <hip/hip_bf16.h>

#define N_NODES 50000
#define N_EDGES 1600000
#define DIM 128
#define N_LAYERS 5
#define NEG 0.2f

typedef unsigned short u16;
typedef unsigned int u32;
using short8 = __attribute__((ext_vector_type(8))) short;
using f32x4  = __attribute__((ext_vector_type(4))) float;

union FragU { uint4 u; short8 s; };

// ---------- helpers ----------
__device__ __forceinline__ float2 bf2x(u32 u) {
    union { u32 i; float f; } lo, hi;
    lo.i = u << 16;
    hi.i = u & 0xffff0000u;
    return make_float2(lo.f, hi.f);
}
__device__ __forceinline__ u16 f2bf(float f) {   // RNE
    union { float f; u32 u; } v; v.f = f;
    u32 r = v.u + 0x7fffu + ((v.u >> 16) & 1u);
    return (u16)(r >> 16);
}
__device__ __forceinline__ u32 pk2(float a, float b) {
    return (u32)f2bf(a) | ((u32)f2bf(b) << 16);
}
__device__ __forceinline__ int clampi(int v) {
    v = (v < 0) ? 0 : v;
    return (v >= N_NODES) ? (N_NODES - 1) : v;
}

// ---------- int-width probe ----------
__global__ void k_probe(const int* __restrict__ ei32, int* __restrict__ flags) {
    __shared__ int cnt;
    int t = threadIdx.x;
    if (t == 0) cnt = 0;
    __syncthreads();
    if (ei32[2 * t + 1] == 0) atomicAdd(&cnt, 1);
    __syncthreads();
    if (t == 0) flags[0] = (cnt >= 255) ? 1 : 0;
}

__device__ __forceinline__ int ldidx(const void* ei, long long i, int m64) {
    int v = m64 ? (int)(((const long long*)ei)[i]) : ((const int*)ei)[i];
    return clampi(v);
}

// ---------- conversions ----------
__global__ void k_cvt_x(const float* __restrict__ x, u16* __restrict__ xb) {
    int i = blockIdx.x * 256 + threadIdx.x;
    float2 v = *(const float2*)(x + (size_t)i * 2);
    ((u32*)xb)[i] = pk2(v.x, v.y);
}

// W -> bf16, transposed [n][k], 16B chunks, XOR swizzle (stride 16 per column)
__global__ void k_cvt_w(const float* __restrict__ Wl, const float* __restrict__ Wr,
                        uint4* __restrict__ Wtg) {
    int id = blockIdx.x * 256 + threadIdx.x;
    if (id >= N_LAYERS * 16 * 256) return;
    int l = id >> 12;
    int rem = id & 4095;
    int kc = rem >> 8;      // 0..15
    int n = rem & 255;      // 0..255
    const float* W = (n < 128) ? (Wl + (size_t)l * DIM * DIM + n)
                               : (Wr + (size_t)l * DIM * DIM + (n - 128));
    u16 c[8];
#pragma unroll
    for (int j = 0; j < 8; ++j) c[j] = f2bf(W[(size_t)(kc * 8 + j) * DIM]);
    uint4 o;
    o.x = (u32)c[0] | ((u32)c[1] << 16);
    o.y = (u32)c[2] | ((u32)c[3] << 16);
    o.z = (u32)c[4] | ((u32)c[5] << 16);
    o.w = (u32)c[6] | ((u32)c[7] << 16);
    Wtg[(size_t)l * 4096 + n * 16 + (kc ^ (n & 15))] = o;
}

// ---------- CSR build (col is u16: 3.2 MB < 4 MB per-XCD L2 -> writes absorbed) ----------
__global__ void k_zero(int* __restrict__ deg) {
    int i = blockIdx.x * 256 + threadIdx.x;
    if (i < N_NODES) deg[i] = 0;
}

__global__ void k_hist(const void* __restrict__ ei, const int* __restrict__ flags,
                       int* __restrict__ deg) {
    int e = blockIdx.x * 256 + threadIdx.x;
    if (e < N_EDGES) {
        int d = ldidx(ei, (long long)N_EDGES + e, flags[0]);
        atomicAdd(&deg[d], 1);
    }
}

// flat scan: 1024 threads x 49 nodes
__global__ void k_scan(const int* __restrict__ deg, int* __restrict__ row_off) {
    __shared__ int sh[1024];
    int tid = threadIdx.x;
    int base = tid * 49;
    int sum = 0;
    for (int i = 0; i < 49; ++i) {
        int idx = base + i;
        if (idx < N_NODES) sum += deg[idx] + 1;   // +1 self loop
    }
    sh[tid] = sum;
    __syncthreads();
    int run = sum;
    for (int off = 1; off < 1024; off <<= 1) {
        int t = (tid >= off) ? sh[tid - off] : 0;
        __syncthreads();
        run += t;
        sh[tid] = run;
        __syncthreads();
    }
    int acc = run - sum;    // exclusive
    for (int i = 0; i < 49; ++i) {
        int idx = base + i;
        if (idx < N_NODES) {
            row_off[idx] = acc;
            acc += deg[idx] + 1;
        }
    }
    if (tid == 1023) row_off[N_NODES] = sh[1023];
}

__global__ void k_rows(const int* __restrict__ row_off, u16* __restrict__ col,
                       int* __restrict__ cursor) {
    int i = blockIdx.x * 256 + threadIdx.x;
    if (i < N_NODES) {
        int c = row_off[i];
        col[c] = (u16)i;     // self loop first
        cursor[i] = c + 1;
    }
}

__global__ void k_fill(const void* __restrict__ ei, const int* __restrict__ flags,
                       int* __restrict__ cursor, u16* __restrict__ col) {
    int e = blockIdx.x * 256 + threadIdx.x;
    if (e < N_EDGES) {
        int s = ldidx(ei, e, flags[0]);
        int d = ldidx(ei, (long long)N_EDGES + e, flags[0]);
        int pos = atomicAdd(&cursor[d], 1);
        col[pos] = (u16)s;
    }
}

// ---------- sort each row by src (perf hint; order-invariant math) ----------
__global__ __launch_bounds__(256) void k_sort(const int* __restrict__ row_off,
                                              u16* __restrict__ col) {
    int gtid = blockIdx.x * 256 + threadIdx.x;
    int row = gtid >> 6;
    int lane = threadIdx.x & 63;
    if (row >= N_NODES) return;
    int beg = row_off[row];
    int end = row_off[row + 1];
    int n = end - beg;
    if (n > 64) n = 64;
    int v = (lane < n) ? (int)col[beg + lane] : 0x7FFFFFFF;
#pragma unroll
    for (int k = 2; k <= 64; k <<= 1) {
#pragma unroll
        for (int j = k >> 1; j > 0; j >>= 1) {
            int pv = __shfl_xor(v, j, 64);
            bool lower = (lane & j) == 0;
            bool asc = (lane & k) == 0;
            int mn = (v < pv) ? v : pv;
            int mx = (v < pv) ? pv : v;
            v = (lower == asc) ? mn : mx;
        }
    }
    if (lane < n) col[beg + lane] = (u16)v;
}

// ---------- MFMA GEMM: [xl|xr] = h_bf16 @ [Wl|Wr] + [bl|br] ----------
__global__ __launch_bounds__(256) void k_mm(
    const u16* __restrict__ hb,
    const uint4* __restrict__ Wtg,
    const float* __restrict__ bl, const float* __restrict__ br,
    u16* __restrict__ xlb,
    float* __restrict__ xr)
{
    __shared__ uint4 wsh[4096];          // 64 KB
    const int tid = threadIdx.x;
#pragma unroll
    for (int i = 0; i < 16; ++i) wsh[tid + i * 256] = Wtg[tid + i * 256];

    const int wave = tid >> 6, lane = tid & 63;
    const int q = lane >> 4, nn = lane & 15;
    const int mA = blockIdx.x * 64 + wave * 16 + nn;

    FragU afr[4];
    const uint4 az = make_uint4(0, 0, 0, 0);
#pragma unroll
    for (int s = 0; s < 4; ++s)
        afr[s].u = (mA < N_NODES)
                 ? *(const uint4*)(hb + (size_t)mA * DIM + s * 32 + q * 8)
                 : az;
    __syncthreads();

    f32x4 acc[16];
#pragma unroll
    for (int i = 0; i < 16; ++i) acc[i] = (f32x4){0.f, 0.f, 0.f, 0.f};

#pragma unroll
    for (int s = 0; s < 4; ++s) {
#pragma unroll
        for (int nt = 0; nt < 16; ++nt) {
            int n = nt * 16 + nn;
            int kc = s * 4 + q;
            FragU b;
            b.u = wsh[n * 16 + (kc ^ (n & 15))];
            acc[nt] = __builtin_amdgcn_mfma_f32_16x16x32_bf16(afr[s].s, b.s, acc[nt], 0, 0, 0);
        }
    }

    const int mBase = blockIdx.x * 64 + wave * 16 + q * 4;
#pragma unroll
    for (int nt = 0; nt < 16; ++nt) {
        int n = nt * 16 + nn;
        bool isL = (n < 128);
        float bv = isL ? bl[n] : br[n - 128];
#pragma unroll
        for (int r = 0; r < 4; ++r) {
            int m = mBase + r;
            if (m < N_NODES) {
                float v = acc[nt][r] + bv;
                if (isL) xlb[(size_t)m * DIM + n] = f2bf(v);
                else     xr[(size_t)m * DIM + (n - 128)] = v;
            }
        }
    }
}

// ---------- fused edge phase: batch-4 gather pipeline ----------
// One wave per dst node; 4 chains x 16 dim-lanes; each chain loads 4 rows
// back-to-back (16 loads in flight per wave), then computes them.
template <int RELU>
__global__ __launch_bounds__(256) void k_edge(
    const u16* __restrict__ xlb, const float* __restrict__ xr,
    const int* __restrict__ row_off, const u16* __restrict__ col,
    const float* __restrict__ att, const float* __restrict__ bias,
    u16* __restrict__ hout)
{
    int gtid = blockIdx.x * 256 + threadIdx.x;
    int node = gtid >> 6;
    int lane = threadIdx.x & 63;
    int g = lane >> 4;
    int t = lane & 15;
    if (node >= N_NODES) return;

    const int d0 = t * 8;
    float4 xr0 = *(const float4*)(xr + (size_t)node * DIM + d0);
    float4 xr1 = *(const float4*)(xr + (size_t)node * DIM + d0 + 4);
    float4 at0 = *(const float4*)(att + d0);
    float4 at1 = *(const float4*)(att + d0 + 4);

    float acc[8];
#pragma unroll
    for (int i = 0; i < 8; ++i) acc[i] = 0.f;
    float lsum = 0.f;

    const int beg = row_off[node];
    const int end = row_off[node + 1];

    for (int j0 = beg + g; j0 < end; j0 += 16) {
        // load phase: up to 4 rows for this chain
        uint4 u[4];
#pragma unroll
        for (int b = 0; b < 4; ++b) {
            int jb = j0 + b * 4;
            if (jb < end) {
                int s = (int)col[jb];
                u[b] = *(const uint4*)(xlb + (size_t)s * DIM + d0);
            }
        }
        // compute phase
#pragma unroll
        for (int b = 0; b < 4; ++b) {
            int jb = j0 + b * 4;
            if (jb >= end) break;
            float2 p0 = bf2x(u[b].x), p1 = bf2x(u[b].y), p2 = bf2x(u[b].z), p3 = bf2x(u[b].w);
            float v0 = p0.x + xr0.x, v1 = p0.y + xr0.y, v2 = p1.x + xr0.z, v3 = p1.y + xr0.w;
            float v4 = p2.x + xr1.x, v5 = p2.y + xr1.y, v6 = p3.x + xr1.z, v7 = p3.y + xr1.w;
            v0 = (v0 > 0.f) ? v0 : NEG * v0;
            v1 = (v1 > 0.f) ? v1 : NEG * v1;
            v2 = (v2 > 0.f) ? v2 : NEG * v2;
            v3 = (v3 > 0.f) ? v3 : NEG * v3;
            v4 = (v4 > 0.f) ? v4 : NEG * v4;
            v5 = (v5 > 0.f) ? v5 : NEG * v5;
            v6 = (v6 > 0.f) ? v6 : NEG * v6;
            v7 = (v7 > 0.f) ? v7 : NEG * v7;
            float p = at0.x * v0;
            p = fmaf(at0.y, v1, p);
            p = fmaf(at0.z, v2, p);
            p = fmaf(at0.w, v3, p);
            p = fmaf(at1.x, v4, p);
            p = fmaf(at1.y, v5, p);
            p = fmaf(at1.z, v6, p);
            p = fmaf(at1.w, v7, p);
            p += __shfl_xor(p, 1, 64);
            p += __shfl_xor(p, 2, 64);
            p += __shfl_xor(p, 4, 64);
            p += __shfl_xor(p, 8, 64);

            float w = __expf(p);
            lsum += w;
            acc[0] = fmaf(w, p0.x, acc[0]);
            acc[1] = fmaf(w, p0.y, acc[1]);
            acc[2] = fmaf(w, p1.x, acc[2]);
            acc[3] = fmaf(w, p1.y, acc[3]);
            acc[4] = fmaf(w, p2.x, acc[4]);
            acc[5] = fmaf(w, p2.y, acc[5]);
            acc[6] = fmaf(w, p3.x, acc[6]);
            acc[7] = fmaf(w, p3.y, acc[7]);
        }
    }

#pragma unroll
    for (int i = 0; i < 8; ++i) {
        acc[i] += __shfl_xor(acc[i], 16, 64);
        acc[i] += __shfl_xor(acc[i], 32, 64);
    }
    lsum += __shfl_xor(lsum, 16, 64);
    lsum += __shfl_xor(lsum, 32, 64);

    if (g == 0) {
        float inv = 1.f / fmaxf(lsum, 1e-16f);
        float4 b0 = *(const float4*)(bias + d0);
        float4 b1 = *(const float4*)(bias + d0 + 4);
        float o0 = acc[0] * inv + b0.x;
        float o1 = acc[1] * inv + b0.y;
        float o2 = acc[2] * inv + b0.z;
        float o3 = acc[3] * inv + b0.w;
        float o4 = acc[4] * inv + b1.x;
        float o5 = acc[5] * inv + b1.y;
        float o6 = acc[6] * inv + b1.z;
        float o7 = acc[7] * inv + b1.w;
        if (RELU) {
            o0 = fmaxf(o0, 0.f); o1 = fmaxf(o1, 0.f);
            o2 = fmaxf(o2, 0.f); o3 = fmaxf(o3, 0.f);
            o4 = fmaxf(o4, 0.f); o5 = fmaxf(o5, 0.f);
            o6 = fmaxf(o6, 0.f); o7 = fmaxf(o7, 0.f);
        }
        uint4 o;
        o.x = pk2(o0, o1);
        o.y = pk2(o2, o3);
        o.z = pk2(o4, o5);
        o.w = pk2(o6, o7);
        *(uint4*)(hout + (size_t)node * DIM + d0) = o;
    }
}

// ---------- mean pool (bf16 h) ----------
__global__ void k_mean_part(const u16* __restrict__ hb, float* __restrict__ part) {
    int d = threadIdx.x;
    int b = blockIdx.x;
    int n0 = b * 200;
    float s = 0.f;
    for (int i = 0; i < 200; ++i) {
        union { u32 i; float f; } v;
        v.i = (u32)hb[(size_t)(n0 + i) * DIM + d] << 16;
        s += v.f;
    }
    part[b * DIM + d] = s;
}

__global__ void k_mean_final(const float* __restrict__ part, float* __restrict__ out) {
    int d = threadIdx.x;
    float s = 0.f;
    for (int b = 0; b < 250; ++b) s += part[b * DIM + d];
    out[d] = s * (1.f / (float)N_NODES);
}

// ---------- launch ----------
extern "C" void kernel_launch(void* const* d_in, const int* in_sizes, int n_in,
                              void* d_out, int out_size, void* d_ws, size_t ws_size,
                              hipStream_t stream) {
    int ix, iei, iWl, ibl, iWr, ibr, iatt, ibias;
    if (in_sizes[0] == N_NODES * DIM) {
        ix = 0; iei = 1; iWl = 2; ibl = 3; iWr = 4; ibr = 5; iatt = 6; ibias = 7;
    } else {
        iWl = 0; iWr = 1; iatt = 2; ibias = 3; ibl = 4; ibr = 5; iei = 6; ix = 7;
    }
    const float* x    = (const float*)d_in[ix];
    const void*  ei   = d_in[iei];
    const float* Wl   = (const float*)d_in[iWl];
    const float* bl   = (const float*)d_in[ibl];
    const float* Wr   = (const float*)d_in[iWr];
    const float* br   = (const float*)d_in[ibr];
    const float* att  = (const float*)d_in[iatt];
    const float* bias = (const float*)d_in[ibias];
    float* out = (float*)d_out;

    char* w = (char*)d_ws;
    float* xr = (float*)w;        w += (size_t)N_NODES * DIM * 4;
    float* part = (float*)w;      w += (size_t)256 * DIM * 4;
    uint4* Wtg = (uint4*)w;       w += (size_t)N_LAYERS * 4096 * 16;
    u16* xb  = (u16*)w;           w += (size_t)N_NODES * DIM * 2;
    u16* hb  = (u16*)w;           w += (size_t)N_NODES * DIM * 2;
    u16* xlb = (u16*)w;           w += (size_t)N_NODES * DIM * 2;
    int* deg = (int*)w;           w += (size_t)N_NODES * 4;
    int* row_off = (int*)w;       w += (size_t)(N_NODES + 4) * 4;
    int* cursor = (int*)w;        w += (size_t)N_NODES * 4;
    int* flags = (int*)w;         w += 64;
    u16* col = (u16*)w;           // (N_EDGES + N_NODES) u16 = 3.3 MB

    k_probe<<<1, 256, 0, stream>>>((const int*)ei, flags);
    k_cvt_x<<<(N_NODES * DIM / 2 + 255) / 256, 256, 0, stream>>>(x, xb);
    k_cvt_w<<<(N_LAYERS * 4096 + 255) / 256, 256, 0, stream>>>(Wl, Wr, Wtg);
    k_zero<<<(N_NODES + 255) / 256, 256, 0, stream>>>(deg);
    k_hist<<<(N_EDGES + 255) / 256, 256, 0, stream>>>(ei, flags, deg);
    k_scan<<<1, 1024, 0, stream>>>(deg, row_off);
    k_rows<<<(N_NODES + 255) / 256, 256, 0, stream>>>(row_off, col, cursor);
    k_fill<<<(N_EDGES + 255) / 256, 256, 0, stream>>>(ei, flags, cursor, col);
    k_sort<<<(N_NODES * 64 + 255) / 256, 256, 0, stream>>>(row_off, col);

    const int mm_grid = (N_NODES + 63) / 64;
    const int edge_grid = (N_NODES * 64 + 255) / 256;

    for (int layer = 0; layer < N_LAYERS; ++layer) {
        const uint4* Wp = Wtg + (size_t)layer * 4096;
        const float* blp = bl + (size_t)layer * DIM;
        const float* brp = br + (size_t)layer * DIM;
        const float* ap  = att + (size_t)layer * DIM;
        const float* bp  = bias + (size_t)layer * DIM;

        const u16* hin = (layer == 0) ? xb : hb;
        k_mm<<<mm_grid, 256, 0, stream>>>(hin, Wp, blp, brp, xlb, xr);

        if (layer < N_LAYERS - 1)
            k_edge<1><<<edge_grid, 256, 0, stream>>>(xlb, xr, row_off, col, ap, bp, hb);
        else
            k_edge<0><<<edge_grid, 256, 0, stream>>>(xlb, xr, row_off, col, ap, bp, hb);
    }

    k_mean_part<<<250, 128, 0, stream>>>(hb, part);
    k_mean_final<<<1, 128, 0, stream>>>(part, out);
}

// Round 12
// 784.319 us; speedup vs baseline: 1.1175x; 1.1175x over previous
//
#include <hip/hip_runtime.h>
#include <hip/hip_bf16.h>

#define N_NODES 50000
#define N_EDGES 1600000
#define DIM 128
#define N_LAYERS 5
#define NEG 0.2f

#define NBKT 196          // dst >> 8  (50000/256 -> 0..195)
#define BCAP_A 9472       // arena cap per bucket (mean 8163, +14 sigma)
#define PBLK 98           // partition blocks
#define EPB 16384         // edges per partition block
#define SEGCAP 12288      // k_scat staging entries (u16)

typedef unsigned short u16;
typedef unsigned char u8;
typedef unsigned int u32;
using short8 = __attribute__((ext_vector_type(8))) short;
using f32x4  = __attribute__((ext_vector_type(4))) float;

union FragU { uint4 u; short8 s; };

// ---------- helpers ----------
__device__ __forceinline__ float2 bf2x(u32 u) {
    union { u32 i; float f; } lo, hi;
    lo.i = u << 16;
    hi.i = u & 0xffff0000u;
    return make_float2(lo.f, hi.f);
}
__device__ __forceinline__ u16 f2bf(float f) {   // RNE
    union { float f; u32 u; } v; v.f = f;
    u32 r = v.u + 0x7fffu + ((v.u >> 16) & 1u);
    return (u16)(r >> 16);
}
__device__ __forceinline__ u32 pk2(float a, float b) {
    return (u32)f2bf(a) | ((u32)f2bf(b) << 16);
}
__device__ __forceinline__ int clampi(int v) {
    v = (v < 0) ? 0 : v;
    return (v >= N_NODES) ? (N_NODES - 1) : v;
}

// ---------- probe + bcnt zero ----------
__global__ void k_probe(const int* __restrict__ ei32, int* __restrict__ flags,
                        int* __restrict__ bcnt) {
    __shared__ int cnt;
    int t = threadIdx.x;
    if (t == 0) cnt = 0;
    __syncthreads();
    if (ei32[2 * t + 1] == 0) atomicAdd(&cnt, 1);
    if (t < NBKT) bcnt[t] = 0;
    __syncthreads();
    if (t == 0) flags[0] = (cnt >= 255) ? 1 : 0;
}

__device__ __forceinline__ int ldidx(const void* ei, long long i, int m64) {
    int v = m64 ? (int)(((const long long*)ei)[i]) : ((const int*)ei)[i];
    return clampi(v);
}

// ---------- conversions ----------
__global__ void k_cvt_x(const float* __restrict__ x, u16* __restrict__ xb) {
    int i = blockIdx.x * 256 + threadIdx.x;
    float2 v = *(const float2*)(x + (size_t)i * 2);
    ((u32*)xb)[i] = pk2(v.x, v.y);
}

__global__ void k_cvt_w(const float* __restrict__ Wl, const float* __restrict__ Wr,
                        uint4* __restrict__ Wtg) {
    int id = blockIdx.x * 256 + threadIdx.x;
    if (id >= N_LAYERS * 16 * 256) return;
    int l = id >> 12;
    int rem = id & 4095;
    int kc = rem >> 8;
    int n = rem & 255;
    const float* W = (n < 128) ? (Wl + (size_t)l * DIM * DIM + n)
                               : (Wr + (size_t)l * DIM * DIM + (n - 128));
    u16 c[8];
#pragma unroll
    for (int j = 0; j < 8; ++j) c[j] = f2bf(W[(size_t)(kc * 8 + j) * DIM]);
    uint4 o;
    o.x = (u32)c[0] | ((u32)c[1] << 16);
    o.y = (u32)c[2] | ((u32)c[3] << 16);
    o.z = (u32)c[4] | ((u32)c[5] << 16);
    o.w = (u32)c[6] | ((u32)c[7] << 16);
    Wtg[(size_t)l * 4096 + n * 16 + (kc ^ (n & 15))] = o;
}

// ---------- CSR build: LDS-staged bucket partition ----------
// payload u32 = src(16b) | dst_local(8b)<<16
__global__ __launch_bounds__(1024) void k_part(
    const void* __restrict__ ei, const int* __restrict__ flags,
    int* __restrict__ bcnt, u32* __restrict__ bpk)
{
    __shared__ u32 ebuf[EPB];        // 64 KB
    __shared__ u8  bkb[EPB];         // 16 KB
    __shared__ int lh[NBKT];
    __shared__ int lb[NBKT + 1];
    __shared__ int gst[NBKT];
    __shared__ int sc[256];

    const int tid = threadIdx.x;
    const int m64 = flags[0];
    const long long e0 = (long long)blockIdx.x * EPB;

    for (int i = tid; i < NBKT; i += 1024) lh[i] = 0;
    __syncthreads();

    u32 pay[16];
    u32 meta[16];            // b | rank<<8
    int nv = 0;
#pragma unroll
    for (int i = 0; i < 16; ++i) {
        long long e = e0 + i * 1024 + tid;
        if (e < N_EDGES) {
            int s = ldidx(ei, e, m64);
            int d = ldidx(ei, (long long)N_EDGES + e, m64);
            int b = d >> 8;
            int rank = atomicAdd(&lh[b], 1);
            pay[i] = (u32)s | ((u32)(d & 255) << 16);
            meta[i] = (u32)b | ((u32)rank << 8);
            nv = i + 1;
        }
    }
    __syncthreads();

    // exclusive scan of lh -> lb  (Hillis-Steele over 256 slots)
    if (tid < 256) sc[tid] = (tid < NBKT) ? lh[tid] : 0;
    __syncthreads();
    for (int off = 1; off < 256; off <<= 1) {
        int v = 0;
        if (tid < 256 && tid >= off) v = sc[tid - off];
        __syncthreads();
        if (tid < 256) sc[tid] += v;
        __syncthreads();
    }
    if (tid < NBKT) lb[tid] = sc[tid] - lh[tid];   // exclusive
    if (tid == 0) lb[NBKT] = 0;
    // reserve arena space
    if (tid < NBKT) gst[tid] = atomicAdd(&bcnt[tid], lh[tid]);
    __syncthreads();

    // scatter into LDS grouped by bucket
#pragma unroll
    for (int i = 0; i < 16; ++i) {
        if (i < nv) {
            int b = (int)(meta[i] & 255);
            int rank = (int)(meta[i] >> 8);
            int p = lb[b] + rank;
            ebuf[p] = pay[i];
            bkb[p] = (u8)b;
        }
    }
    __syncthreads();

    // coalesced copy-out to arenas
    int total = (e0 + EPB <= N_EDGES) ? EPB : (int)(N_EDGES - e0);
    for (int i = tid; i < total; i += 1024) {
        int b = (int)bkb[i];
        int off = gst[b] + (i - lb[b]);
        if (off < BCAP_A)
            bpk[(size_t)b * BCAP_A + off] = ebuf[i];
    }
}

// per-bucket degree count -> coalesced deg writes
__global__ __launch_bounds__(256) void k_deg(
    const u32* __restrict__ bpk, const int* __restrict__ bcnt,
    const void* __restrict__ ei, const int* __restrict__ flags,
    int* __restrict__ deg)
{
    __shared__ int dh[256];
    int b = blockIdx.x;
    int tid = threadIdx.x;
    dh[tid] = 0;
    __syncthreads();
    int cnt = bcnt[b];
    if (cnt <= BCAP_A) {
        for (int i = tid; i < cnt; i += 256)
            atomicAdd(&dh[(bpk[(size_t)b * BCAP_A + i] >> 16) & 255], 1);
    } else {
        int m64 = flags[0];
        for (long long e = tid; e < N_EDGES; e += 256) {
            int d = ldidx(ei, (long long)N_EDGES + e, m64);
            if ((d >> 8) == b) atomicAdd(&dh[d & 255], 1);
        }
    }
    __syncthreads();
    int d = b * 256 + tid;
    if (d < N_NODES) deg[d] = dh[tid];
}

// flat scan: 1024 threads x 49 nodes
__global__ void k_scan(const int* __restrict__ deg, int* __restrict__ row_off) {
    __shared__ int sh[1024];
    int tid = threadIdx.x;
    int base = tid * 49;
    int sum = 0;
    for (int i = 0; i < 49; ++i) {
        int idx = base + i;
        if (idx < N_NODES) sum += deg[idx] + 1;   // +1 self loop
    }
    sh[tid] = sum;
    __syncthreads();
    int run = sum;
    for (int off = 1; off < 1024; off <<= 1) {
        int t = (tid >= off) ? sh[tid - off] : 0;
        __syncthreads();
        run += t;
        sh[tid] = run;
        __syncthreads();
    }
    int acc = run - sum;
    for (int i = 0; i < 49; ++i) {
        int idx = base + i;
        if (idx < N_NODES) {
            row_off[idx] = acc;
            acc += deg[idx] + 1;
        }
    }
    if (tid == 1023) row_off[N_NODES] = sh[1023];
}

// per-bucket scatter via LDS staging -> coalesced col writes (self-loop first)
__global__ __launch_bounds__(256) void k_scat(
    const u32* __restrict__ bpk, const int* __restrict__ bcnt,
    const int* __restrict__ row_off, u16* __restrict__ col,
    const void* __restrict__ ei, const int* __restrict__ flags)
{
    __shared__ u16 stage[SEGCAP];    // 24 KB
    __shared__ int cur[256];
    int b = blockIdx.x;
    int tid = threadIdx.x;
    int d_lo = b * 256;
    int d_hi = d_lo + 256; if (d_hi > N_NODES) d_hi = N_NODES;
    int base0 = row_off[d_lo];
    int seglen = row_off[d_hi] - base0;

    int d = d_lo + tid;
    if (d < d_hi) {
        int r = row_off[d] - base0;
        if (r < SEGCAP) stage[r] = (u16)d;       // self loop first
        cur[tid] = r + 1;
    }
    __syncthreads();

    int cnt = bcnt[b];
    if (cnt <= BCAP_A) {
        for (int i = tid; i < cnt; i += 256) {
            u32 p = bpk[(size_t)b * BCAP_A + i];
            int pos = atomicAdd(&cur[(p >> 16) & 255], 1);
            if (pos < SEGCAP) stage[pos] = (u16)(p & 0xffff);
        }
    } else {
        int m64 = flags[0];
        for (long long e = tid; e < N_EDGES; e += 256) {
            int dd = ldidx(ei, (long long)N_EDGES + e, m64);
            if ((dd >> 8) == b) {
                int s = ldidx(ei, e, m64);
                int pos = atomicAdd(&cur[dd & 255], 1);
                if (pos < SEGCAP) stage[pos] = (u16)s;
            }
        }
    }
    __syncthreads();
    for (int i = tid; i < seglen; i += 256)
        col[base0 + i] = stage[i];
}

// ---------- MFMA GEMM: [xl|xr] = h_bf16 @ [Wl|Wr] + [bl|br] ----------
__global__ __launch_bounds__(256) void k_mm(
    const u16* __restrict__ hb,
    const uint4* __restrict__ Wtg,
    const float* __restrict__ bl, const float* __restrict__ br,
    u16* __restrict__ xlb,
    float* __restrict__ xr)
{
    __shared__ uint4 wsh[4096];          // 64 KB
    const int tid = threadIdx.x;
#pragma unroll
    for (int i = 0; i < 16; ++i) wsh[tid + i * 256] = Wtg[tid + i * 256];

    const int wave = tid >> 6, lane = tid & 63;
    const int q = lane >> 4, nn = lane & 15;
    const int mA = blockIdx.x * 64 + wave * 16 + nn;

    FragU afr[4];
    const uint4 az = make_uint4(0, 0, 0, 0);
#pragma unroll
    for (int s = 0; s < 4; ++s)
        afr[s].u = (mA < N_NODES)
                 ? *(const uint4*)(hb + (size_t)mA * DIM + s * 32 + q * 8)
                 : az;
    __syncthreads();

    f32x4 acc[16];
#pragma unroll
    for (int i = 0; i < 16; ++i) acc[i] = (f32x4){0.f, 0.f, 0.f, 0.f};

#pragma unroll
    for (int s = 0; s < 4; ++s) {
#pragma unroll
        for (int nt = 0; nt < 16; ++nt) {
            int n = nt * 16 + nn;
            int kc = s * 4 + q;
            FragU b;
            b.u = wsh[n * 16 + (kc ^ (n & 15))];
            acc[nt] = __builtin_amdgcn_mfma_f32_16x16x32_bf16(afr[s].s, b.s, acc[nt], 0, 0, 0);
        }
    }

    const int mBase = blockIdx.x * 64 + wave * 16 + q * 4;
#pragma unroll
    for (int nt = 0; nt < 16; ++nt) {
        int n = nt * 16 + nn;
        bool isL = (n < 128);
        float bv = isL ? bl[n] : br[n - 128];
#pragma unroll
        for (int r = 0; r < 4; ++r) {
            int m = mBase + r;
            if (m < N_NODES) {
                float v = acc[nt][r] + bv;
                if (isL) xlb[(size_t)m * DIM + n] = f2bf(v);
                else     xr[(size_t)m * DIM + (n - 128)] = v;
            }
        }
    }
}

// ---------- fused edge phase: register col + batch-8 volleys ----------
template <int RELU>
__global__ __launch_bounds__(256) void k_edge(
    const u16* __restrict__ xlb, const float* __restrict__ xr,
    const int* __restrict__ row_off, const u16* __restrict__ col,
    const float* __restrict__ att, const float* __restrict__ bias,
    u16* __restrict__ hout)
{
    int gtid = blockIdx.x * 256 + threadIdx.x;
    int node = gtid >> 6;
    int lane = threadIdx.x & 63;
    int g = lane >> 4;
    int t = lane & 15;
    if (node >= N_NODES) return;

    const int d0 = t * 8;
    float4 xr0 = *(const float4*)(xr + (size_t)node * DIM + d0);
    float4 xr1 = *(const float4*)(xr + (size_t)node * DIM + d0 + 4);
    float4 at0 = *(const float4*)(att + d0);
    float4 at1 = *(const float4*)(att + d0 + 4);

    const int beg = row_off[node];
    const int end = row_off[node + 1];
    const int n = end - beg;
    const int nreg = (n < 64) ? n : 64;

    // whole row's src indices into registers (one coalesced u16 load)
    int idx = (lane < nreg) ? (int)col[beg + lane] : 0;

    float acc[8];
#pragma unroll
    for (int i = 0; i < 8; ++i) acc[i] = 0.f;
    float lsum = 0.f;

    const u16* basep = xlb + d0;

#pragma unroll 1
    for (int k0 = 0; k0 < 16; k0 += 8) {
        uint4 u[8];
        // volley: up to 8 gathers in flight for this chain
#pragma unroll
        for (int k = 0; k < 8; ++k) {
            int p = g + 4 * (k0 + k);
            int ps = (p < nreg) ? p : 0;
            int s = __shfl(idx, ps, 64);          // all lanes active
            if (p < nreg)
                u[k] = *(const uint4*)(basep + (size_t)s * DIM);
        }
        // compute
#pragma unroll
        for (int k = 0; k < 8; ++k) {
            int p = g + 4 * (k0 + k);
            if (p < nreg) {
                float2 p0 = bf2x(u[k].x), p1 = bf2x(u[k].y), p2 = bf2x(u[k].z), p3 = bf2x(u[k].w);
                float v0 = p0.x + xr0.x, v1 = p0.y + xr0.y, v2 = p1.x + xr0.z, v3 = p1.y + xr0.w;
                float v4 = p2.x + xr1.x, v5 = p2.y + xr1.y, v6 = p3.x + xr1.z, v7 = p3.y + xr1.w;
                v0 = fmaxf(v0, NEG * v0);
                v1 = fmaxf(v1, NEG * v1);
                v2 = fmaxf(v2, NEG * v2);
                v3 = fmaxf(v3, NEG * v3);
                v4 = fmaxf(v4, NEG * v4);
                v5 = fmaxf(v5, NEG * v5);
                v6 = fmaxf(v6, NEG * v6);
                v7 = fmaxf(v7, NEG * v7);
                float pp = at0.x * v0;
                pp = fmaf(at0.y, v1, pp);
                pp = fmaf(at0.z, v2, pp);
                pp = fmaf(at0.w, v3, pp);
                pp = fmaf(at1.x, v4, pp);
                pp = fmaf(at1.y, v5, pp);
                pp = fmaf(at1.z, v6, pp);
                pp = fmaf(at1.w, v7, pp);
                pp += __shfl_xor(pp, 1, 64);
                pp += __shfl_xor(pp, 2, 64);
                pp += __shfl_xor(pp, 4, 64);
                pp += __shfl_xor(pp, 8, 64);
                float w = __expf(pp);
                lsum += w;
                acc[0] = fmaf(w, p0.x, acc[0]);
                acc[1] = fmaf(w, p0.y, acc[1]);
                acc[2] = fmaf(w, p1.x, acc[2]);
                acc[3] = fmaf(w, p1.y, acc[3]);
                acc[4] = fmaf(w, p2.x, acc[4]);
                acc[5] = fmaf(w, p2.y, acc[5]);
                acc[6] = fmaf(w, p3.x, acc[6]);
                acc[7] = fmaf(w, p3.y, acc[7]);
            }
        }
    }

    // rare tail: rows longer than 64
    for (int j = beg + 64 + g; j < end; j += 4) {
        int s = (int)col[j];
        uint4 u = *(const uint4*)(basep + (size_t)s * DIM);
        float2 p0 = bf2x(u.x), p1 = bf2x(u.y), p2 = bf2x(u.z), p3 = bf2x(u.w);
        float v0 = p0.x + xr0.x, v1 = p0.y + xr0.y, v2 = p1.x + xr0.z, v3 = p1.y + xr0.w;
        float v4 = p2.x + xr1.x, v5 = p2.y + xr1.y, v6 = p3.x + xr1.z, v7 = p3.y + xr1.w;
        v0 = fmaxf(v0, NEG * v0); v1 = fmaxf(v1, NEG * v1);
        v2 = fmaxf(v2, NEG * v2); v3 = fmaxf(v3, NEG * v3);
        v4 = fmaxf(v4, NEG * v4); v5 = fmaxf(v5, NEG * v5);
        v6 = fmaxf(v6, NEG * v6); v7 = fmaxf(v7, NEG * v7);
        float pp = at0.x * v0;
        pp = fmaf(at0.y, v1, pp);
        pp = fmaf(at0.z, v2, pp);
        pp = fmaf(at0.w, v3, pp);
        pp = fmaf(at1.x, v4, pp);
        pp = fmaf(at1.y, v5, pp);
        pp = fmaf(at1.z, v6, pp);
        pp = fmaf(at1.w, v7, pp);
        pp += __shfl_xor(pp, 1, 64);
        pp += __shfl_xor(pp, 2, 64);
        pp += __shfl_xor(pp, 4, 64);
        pp += __shfl_xor(pp, 8, 64);
        float w = __expf(pp);
        lsum += w;
        acc[0] = fmaf(w, p0.x, acc[0]);
        acc[1] = fmaf(w, p0.y, acc[1]);
        acc[2] = fmaf(w, p1.x, acc[2]);
        acc[3] = fmaf(w, p1.y, acc[3]);
        acc[4] = fmaf(w, p2.x, acc[4]);
        acc[5] = fmaf(w, p2.y, acc[5]);
        acc[6] = fmaf(w, p3.x, acc[6]);
        acc[7] = fmaf(w, p3.y, acc[7]);
    }

#pragma unroll
    for (int i = 0; i < 8; ++i) {
        acc[i] += __shfl_xor(acc[i], 16, 64);
        acc[i] += __shfl_xor(acc[i], 32, 64);
    }
    lsum += __shfl_xor(lsum, 16, 64);
    lsum += __shfl_xor(lsum, 32, 64);

    if (g == 0) {
        float inv = 1.f / fmaxf(lsum, 1e-16f);
        float4 b0 = *(const float4*)(bias + d0);
        float4 b1 = *(const float4*)(bias + d0 + 4);
        float o0 = acc[0] * inv + b0.x;
        float o1 = acc[1] * inv + b0.y;
        float o2 = acc[2] * inv + b0.z;
        float o3 = acc[3] * inv + b0.w;
        float o4 = acc[4] * inv + b1.x;
        float o5 = acc[5] * inv + b1.y;
        float o6 = acc[6] * inv + b1.z;
        float o7 = acc[7] * inv + b1.w;
        if (RELU) {
            o0 = fmaxf(o0, 0.f); o1 = fmaxf(o1, 0.f);
            o2 = fmaxf(o2, 0.f); o3 = fmaxf(o3, 0.f);
            o4 = fmaxf(o4, 0.f); o5 = fmaxf(o5, 0.f);
            o6 = fmaxf(o6, 0.f); o7 = fmaxf(o7, 0.f);
        }
        uint4 o;
        o.x = pk2(o0, o1);
        o.y = pk2(o2, o3);
        o.z = pk2(o4, o5);
        o.w = pk2(o6, o7);
        *(uint4*)(hout + (size_t)node * DIM + d0) = o;
    }
}

// ---------- mean pool (bf16 h) ----------
__global__ void k_mean_part(const u16* __restrict__ hb, float* __restrict__ part) {
    int d = threadIdx.x;
    int b = blockIdx.x;
    int n0 = b * 200;
    float s = 0.f;
    for (int i = 0; i < 200; ++i) {
        union { u32 i; float f; } v;
        v.i = (u32)hb[(size_t)(n0 + i) * DIM + d] << 16;
        s += v.f;
    }
    part[b * DIM + d] = s;
}

__global__ void k_mean_final(const float* __restrict__ part, float* __restrict__ out) {
    int d = threadIdx.x;
    float s = 0.f;
    for (int b = 0; b < 250; ++b) s += part[b * DIM + d];
    out[d] = s * (1.f / (float)N_NODES);
}

// ---------- launch ----------
extern "C" void kernel_launch(void* const* d_in, const int* in_sizes, int n_in,
                              void* d_out, int out_size, void* d_ws, size_t ws_size,
                              hipStream_t stream) {
    int ix, iei, iWl, ibl, iWr, ibr, iatt, ibias;
    if (in_sizes[0] == N_NODES * DIM) {
        ix = 0; iei = 1; iWl = 2; ibl = 3; iWr = 4; ibr = 5; iatt = 6; ibias = 7;
    } else {
        iWl = 0; iWr = 1; iatt = 2; ibias = 3; ibl = 4; ibr = 5; iei = 6; ix = 7;
    }
    const float* x    = (const float*)d_in[ix];
    const void*  ei   = d_in[iei];
    const float* Wl   = (const float*)d_in[iWl];
    const float* bl   = (const float*)d_in[ibl];
    const float* Wr   = (const float*)d_in[iWr];
    const float* br   = (const float*)d_in[ibr];
    const float* att  = (const float*)d_in[iatt];
    const float* bias = (const float*)d_in[ibias];
    float* out = (float*)d_out;

    char* w = (char*)d_ws;
    float* xr = (float*)w;        w += (size_t)N_NODES * DIM * 4;
    float* part = (float*)w;      w += (size_t)256 * DIM * 4;
    uint4* Wtg = (uint4*)w;       w += (size_t)N_LAYERS * 4096 * 16;
    u16* xb  = (u16*)w;           w += (size_t)N_NODES * DIM * 2;
    u16* hb  = (u16*)w;           w += (size_t)N_NODES * DIM * 2;
    u16* xlb = (u16*)w;           w += (size_t)N_NODES * DIM * 2;
    int* deg = (int*)w;           w += (size_t)(NBKT * 256 + 4) * 4;
    int* row_off = (int*)w;       w += (size_t)(N_NODES + 4) * 4;
    int* flags = (int*)w;         w += 64;
    int* bcnt = (int*)w;          w += (size_t)(NBKT + 4) * 4;
    u32* bpk = (u32*)w;           w += (size_t)NBKT * BCAP_A * 4;
    u16* col = (u16*)w;           w += (size_t)(N_EDGES + N_NODES + 64) * 2;

    k_probe<<<1, 256, 0, stream>>>((const int*)ei, flags, bcnt);
    k_cvt_x<<<(N_NODES * DIM / 2 + 255) / 256, 256, 0, stream>>>(x, xb);
    k_cvt_w<<<(N_LAYERS * 4096 + 255) / 256, 256, 0, stream>>>(Wl, Wr, Wtg);
    k_part<<<PBLK, 1024, 0, stream>>>(ei, flags, bcnt, bpk);
    k_deg<<<NBKT, 256, 0, stream>>>(bpk, bcnt, ei, flags, deg);
    k_scan<<<1, 1024, 0, stream>>>(deg, row_off);
    k_scat<<<NBKT, 256, 0, stream>>>(bpk, bcnt, row_off, col, ei, flags);

    const int mm_grid = (N_NODES + 63) / 64;
    const int edge_grid = (N_NODES * 64 + 255) / 256;

    for (int layer = 0; layer < N_LAYERS; ++layer) {
        const uint4* Wp = Wtg + (size_t)layer * 4096;
        const float* blp = bl + (size_t)layer * DIM;
        const float* brp = br + (size_t)layer * DIM;
        const float* ap  = att + (size_t)layer * DIM;
        const float* bp  = bias + (size_t)layer * DIM;

        const u16* hin = (layer == 0) ? xb : hb;
        k_mm<<<mm_grid, 256, 0, stream>>>(hin, Wp, blp, brp, xlb, xr);

        if (layer < N_LAYERS - 1)
            k_edge<1><<<edge_grid, 256, 0, stream>>>(xlb, xr, row_off, col, ap, bp, hb);
        else
            k_edge<0><<<edge_grid, 256, 0, stream>>>(xlb, xr, row_off, col, ap, bp, hb);
    }

    k_mean_part<<<250, 128, 0, stream>>>(hb, part);
    k_mean_final<<<1, 128, 0, stream>>>(part, out);
}

// Round 13
// 700.029 us; speedup vs baseline: 1.2521x; 1.1204x over previous
//
#include <hip/hip_runtime.h>
#include <hip/hip_bf16.h>

#define N_NODES 50000
#define N_EDGES 1600000
#define DIM 128
#define N_LAYERS 5
#define NEG 0.2f

#define NBKT 196          // dst >> 8
#define BCAP_A 9472       // arena cap per bucket (mean 8163)
#define PBLK 98           // partition blocks
#define EPB 16384         // edges per partition block
#define SEGCAP 12288      // k_scat staging entries (u16)

typedef unsigned short u16;
typedef unsigned char u8;
typedef unsigned int u32;
using short8 = __attribute__((ext_vector_type(8))) short;
using f32x4  = __attribute__((ext_vector_type(4))) float;

union FragU { uint4 u; short8 s; };

// ---------- helpers ----------
__device__ __forceinline__ float2 bf2x(u32 u) {
    union { u32 i; float f; } lo, hi;
    lo.i = u << 16;
    hi.i = u & 0xffff0000u;
    return make_float2(lo.f, hi.f);
}
__device__ __forceinline__ u16 f2bf(float f) {   // RNE
    union { float f; u32 u; } v; v.f = f;
    u32 r = v.u + 0x7fffu + ((v.u >> 16) & 1u);
    return (u16)(r >> 16);
}
__device__ __forceinline__ u32 pk2(float a, float b) {
    return (u32)f2bf(a) | ((u32)f2bf(b) << 16);
}
__device__ __forceinline__ int clampi(int v) {
    v = (v < 0) ? 0 : v;
    return (v >= N_NODES) ? (N_NODES - 1) : v;
}

// ---------- probe + bcnt zero ----------
__global__ void k_probe(const int* __restrict__ ei32, int* __restrict__ flags,
                        int* __restrict__ bcnt) {
    __shared__ int cnt;
    int t = threadIdx.x;
    if (t == 0) cnt = 0;
    __syncthreads();
    if (ei32[2 * t + 1] == 0) atomicAdd(&cnt, 1);
    if (t < NBKT) bcnt[t] = 0;
    __syncthreads();
    if (t == 0) flags[0] = (cnt >= 255) ? 1 : 0;
}

__device__ __forceinline__ int ldidx(const void* ei, long long i, int m64) {
    int v = m64 ? (int)(((const long long*)ei)[i]) : ((const int*)ei)[i];
    return clampi(v);
}

// ---------- conversions ----------
__global__ void k_cvt_x(const float* __restrict__ x, u16* __restrict__ xb) {
    int i = blockIdx.x * 256 + threadIdx.x;
    float2 v = *(const float2*)(x + (size_t)i * 2);
    ((u32*)xb)[i] = pk2(v.x, v.y);
}

__global__ void k_cvt_w(const float* __restrict__ Wl, const float* __restrict__ Wr,
                        uint4* __restrict__ Wtg) {
    int id = blockIdx.x * 256 + threadIdx.x;
    if (id >= N_LAYERS * 16 * 256) return;
    int l = id >> 12;
    int rem = id & 4095;
    int kc = rem >> 8;
    int n = rem & 255;
    const float* W = (n < 128) ? (Wl + (size_t)l * DIM * DIM + n)
                               : (Wr + (size_t)l * DIM * DIM + (n - 128));
    u16 c[8];
#pragma unroll
    for (int j = 0; j < 8; ++j) c[j] = f2bf(W[(size_t)(kc * 8 + j) * DIM]);
    uint4 o;
    o.x = (u32)c[0] | ((u32)c[1] << 16);
    o.y = (u32)c[2] | ((u32)c[3] << 16);
    o.z = (u32)c[4] | ((u32)c[5] << 16);
    o.w = (u32)c[6] | ((u32)c[7] << 16);
    Wtg[(size_t)l * 4096 + n * 16 + (kc ^ (n & 15))] = o;
}

// ---------- CSR build: LDS-staged bucket partition ----------
__global__ __launch_bounds__(1024) void k_part(
    const void* __restrict__ ei, const int* __restrict__ flags,
    int* __restrict__ bcnt, u32* __restrict__ bpk)
{
    __shared__ u32 ebuf[EPB];        // 64 KB
    __shared__ u8  bkb[EPB];         // 16 KB
    __shared__ int lh[NBKT];
    __shared__ int lb[NBKT + 1];
    __shared__ int gst[NBKT];
    __shared__ int sc[256];

    const int tid = threadIdx.x;
    const int m64 = flags[0];
    const long long e0 = (long long)blockIdx.x * EPB;

    for (int i = tid; i < NBKT; i += 1024) lh[i] = 0;
    __syncthreads();

    u32 pay[16];
    u32 meta[16];            // b | rank<<8
    int nv = 0;
#pragma unroll
    for (int i = 0; i < 16; ++i) {
        long long e = e0 + i * 1024 + tid;
        if (e < N_EDGES) {
            int s = ldidx(ei, e, m64);
            int d = ldidx(ei, (long long)N_EDGES + e, m64);
            int b = d >> 8;
            int rank = atomicAdd(&lh[b], 1);
            pay[i] = (u32)s | ((u32)(d & 255) << 16);
            meta[i] = (u32)b | ((u32)rank << 8);
            nv = i + 1;
        }
    }
    __syncthreads();

    if (tid < 256) sc[tid] = (tid < NBKT) ? lh[tid] : 0;
    __syncthreads();
    for (int off = 1; off < 256; off <<= 1) {
        int v = 0;
        if (tid < 256 && tid >= off) v = sc[tid - off];
        __syncthreads();
        if (tid < 256) sc[tid] += v;
        __syncthreads();
    }
    if (tid < NBKT) lb[tid] = sc[tid] - lh[tid];
    if (tid == 0) lb[NBKT] = 0;
    if (tid < NBKT) gst[tid] = atomicAdd(&bcnt[tid], lh[tid]);
    __syncthreads();

#pragma unroll
    for (int i = 0; i < 16; ++i) {
        if (i < nv) {
            int b = (int)(meta[i] & 255);
            int rank = (int)(meta[i] >> 8);
            int p = lb[b] + rank;
            ebuf[p] = pay[i];
            bkb[p] = (u8)b;
        }
    }
    __syncthreads();

    int total = (e0 + EPB <= N_EDGES) ? EPB : (int)(N_EDGES - e0);
    for (int i = tid; i < total; i += 1024) {
        int b = (int)bkb[i];
        int off = gst[b] + (i - lb[b]);
        if (off < BCAP_A)
            bpk[(size_t)b * BCAP_A + off] = ebuf[i];
    }
}

// per-bucket degree + LOCAL row_off scan + bucket total
__global__ __launch_bounds__(256) void k_deg(
    const u32* __restrict__ bpk, const int* __restrict__ bcnt,
    const void* __restrict__ ei, const int* __restrict__ flags,
    int* __restrict__ row_off, int* __restrict__ btot)
{
    __shared__ int dh[256];
    __shared__ int sc[256];
    int b = blockIdx.x;
    int tid = threadIdx.x;
    dh[tid] = 0;
    __syncthreads();
    int cnt = bcnt[b];
    if (cnt <= BCAP_A) {
        for (int i = tid; i < cnt; i += 256)
            atomicAdd(&dh[(bpk[(size_t)b * BCAP_A + i] >> 16) & 255], 1);
    } else {
        int m64 = flags[0];
        for (long long e = tid; e < N_EDGES; e += 256) {
            int d = ldidx(ei, (long long)N_EDGES + e, m64);
            if ((d >> 8) == b) atomicAdd(&dh[d & 255], 1);
        }
    }
    __syncthreads();
    int d = b * 256 + tid;
    int v = (d < N_NODES) ? (dh[tid] + 1) : 0;    // +1 self loop
    sc[tid] = v;
    __syncthreads();
    for (int off = 1; off < 256; off <<= 1) {
        int t = (tid >= off) ? sc[tid - off] : 0;
        __syncthreads();
        sc[tid] += t;
        __syncthreads();
    }
    if (d < N_NODES) row_off[d] = sc[tid] - v;    // local exclusive
    if (tid == 255) btot[b] = sc[255];
}

// scan 196 bucket totals -> boff; grand total -> row_off[N_NODES]
__global__ void k_bscan(const int* __restrict__ btot, int* __restrict__ boff,
                        int* __restrict__ row_off) {
    __shared__ int sc[256];
    int tid = threadIdx.x;
    int v = (tid < NBKT) ? btot[tid] : 0;
    sc[tid] = v;
    __syncthreads();
    for (int off = 1; off < 256; off <<= 1) {
        int t = (tid >= off) ? sc[tid - off] : 0;
        __syncthreads();
        sc[tid] += t;
        __syncthreads();
    }
    if (tid < NBKT) boff[tid] = sc[tid] - v;
    if (tid == NBKT - 1) row_off[N_NODES] = sc[tid];
}

// per-bucket scatter via LDS staging -> coalesced col writes; absolutize row_off
__global__ __launch_bounds__(256) void k_scat(
    const u32* __restrict__ bpk, const int* __restrict__ bcnt,
    int* __restrict__ row_off, const int* __restrict__ boff,
    const int* __restrict__ btot, u16* __restrict__ col,
    const void* __restrict__ ei, const int* __restrict__ flags)
{
    __shared__ u16 stage[SEGCAP];    // 24 KB
    __shared__ int cur[256];
    int b = blockIdx.x;
    int tid = threadIdx.x;
    int d_lo = b * 256;
    int d_hi = d_lo + 256; if (d_hi > N_NODES) d_hi = N_NODES;
    int base0 = boff[b];
    int seglen = btot[b];
    if (seglen > SEGCAP) seglen = SEGCAP;

    int d = d_lo + tid;
    int rloc = 0;
    if (d < d_hi) {
        rloc = row_off[d];                       // local
        if (rloc < SEGCAP) stage[rloc] = (u16)d; // self loop first
        cur[tid] = rloc + 1;
    }
    __syncthreads();

    int cnt = bcnt[b];
    if (cnt <= BCAP_A) {
        for (int i = tid; i < cnt; i += 256) {
            u32 p = bpk[(size_t)b * BCAP_A + i];
            int pos = atomicAdd(&cur[(p >> 16) & 255], 1);
            if (pos < SEGCAP) stage[pos] = (u16)(p & 0xffff);
        }
    } else {
        int m64 = flags[0];
        for (long long e = tid; e < N_EDGES; e += 256) {
            int dd = ldidx(ei, (long long)N_EDGES + e, m64);
            if ((dd >> 8) == b) {
                int s = ldidx(ei, e, m64);
                int pos = atomicAdd(&cur[dd & 255], 1);
                if (pos < SEGCAP) stage[pos] = (u16)s;
            }
        }
    }
    __syncthreads();
    for (int i = tid; i < seglen; i += 256)
        col[base0 + i] = stage[i];
    if (d < d_hi) row_off[d] = base0 + rloc;     // absolutize (own bucket only)
}

// ---------- MFMA GEMM: [xl|xr] = h_bf16 @ [Wl|Wr] + [bl|br] ----------
__global__ __launch_bounds__(256) void k_mm(
    const u16* __restrict__ hb,
    const uint4* __restrict__ Wtg,
    const float* __restrict__ bl, const float* __restrict__ br,
    u16* __restrict__ xlb,
    float* __restrict__ xr)
{
    __shared__ uint4 wsh[4096];          // 64 KB
    const int tid = threadIdx.x;
#pragma unroll
    for (int i = 0; i < 16; ++i) wsh[tid + i * 256] = Wtg[tid + i * 256];

    const int wave = tid >> 6, lane = tid & 63;
    const int q = lane >> 4, nn = lane & 15;
    const int mA = blockIdx.x * 64 + wave * 16 + nn;

    FragU afr[4];
    const uint4 az = make_uint4(0, 0, 0, 0);
#pragma unroll
    for (int s = 0; s < 4; ++s)
        afr[s].u = (mA < N_NODES)
                 ? *(const uint4*)(hb + (size_t)mA * DIM + s * 32 + q * 8)
                 : az;
    __syncthreads();

    f32x4 acc[16];
#pragma unroll
    for (int i = 0; i < 16; ++i) acc[i] = (f32x4){0.f, 0.f, 0.f, 0.f};

#pragma unroll
    for (int s = 0; s < 4; ++s) {
#pragma unroll
        for (int nt = 0; nt < 16; ++nt) {
            int n = nt * 16 + nn;
            int kc = s * 4 + q;
            FragU b;
            b.u = wsh[n * 16 + (kc ^ (n & 15))];
            acc[nt] = __builtin_amdgcn_mfma_f32_16x16x32_bf16(afr[s].s, b.s, acc[nt], 0, 0, 0);
        }
    }

    const int mBase = blockIdx.x * 64 + wave * 16 + q * 4;
#pragma unroll
    for (int nt = 0; nt < 16; ++nt) {
        int n = nt * 16 + nn;
        bool isL = (n < 128);
        float bv = isL ? bl[n] : br[n - 128];
#pragma unroll
        for (int r = 0; r < 4; ++r) {
            int m = mBase + r;
            if (m < N_NODES) {
                float v = acc[nt][r] + bv;
                if (isL) xlb[(size_t)m * DIM + n] = f2bf(v);
                else     xr[(size_t)m * DIM + (n - 128)] = v;
            }
        }
    }
}

// ---------- fused edge phase: register col + batch-8 volleys ----------
template <int RELU>
__global__ __launch_bounds__(256) void k_edge(
    const u16* __restrict__ xlb, const float* __restrict__ xr,
    const int* __restrict__ row_off, const u16* __restrict__ col,
    const float* __restrict__ att, const float* __restrict__ bias,
    u16* __restrict__ hout)
{
    int gtid = blockIdx.x * 256 + threadIdx.x;
    int node = gtid >> 6;
    int lane = threadIdx.x & 63;
    int g = lane >> 4;
    int t = lane & 15;
    if (node >= N_NODES) return;

    const int d0 = t * 8;
    float4 xr0 = *(const float4*)(xr + (size_t)node * DIM + d0);
    float4 xr1 = *(const float4*)(xr + (size_t)node * DIM + d0 + 4);
    float4 at0 = *(const float4*)(att + d0);
    float4 at1 = *(const float4*)(att + d0 + 4);

    const int beg = row_off[node];
    const int end = row_off[node + 1];
    const int n = end - beg;
    const int nreg = (n < 64) ? n : 64;

    int idx = (lane < nreg) ? (int)col[beg + lane] : 0;

    float acc[8];
#pragma unroll
    for (int i = 0; i < 8; ++i) acc[i] = 0.f;
    float lsum = 0.f;

    const u16* basep = xlb + d0;

#pragma unroll 1
    for (int k0 = 0; k0 < 16; k0 += 8) {
        uint4 u[8];
#pragma unroll
        for (int k = 0; k < 8; ++k) {
            int p = g + 4 * (k0 + k);
            int ps = (p < nreg) ? p : 0;
            int s = __shfl(idx, ps, 64);
            if (p < nreg)
                u[k] = *(const uint4*)(basep + (size_t)s * DIM);
        }
#pragma unroll
        for (int k = 0; k < 8; ++k) {
            int p = g + 4 * (k0 + k);
            if (p < nreg) {
                float2 p0 = bf2x(u[k].x), p1 = bf2x(u[k].y), p2 = bf2x(u[k].z), p3 = bf2x(u[k].w);
                float v0 = p0.x + xr0.x, v1 = p0.y + xr0.y, v2 = p1.x + xr0.z, v3 = p1.y + xr0.w;
                float v4 = p2.x + xr1.x, v5 = p2.y + xr1.y, v6 = p3.x + xr1.z, v7 = p3.y + xr1.w;
                v0 = fmaxf(v0, NEG * v0);
                v1 = fmaxf(v1, NEG * v1);
                v2 = fmaxf(v2, NEG * v2);
                v3 = fmaxf(v3, NEG * v3);
                v4 = fmaxf(v4, NEG * v4);
                v5 = fmaxf(v5, NEG * v5);
                v6 = fmaxf(v6, NEG * v6);
                v7 = fmaxf(v7, NEG * v7);
                float pp = at0.x * v0;
                pp = fmaf(at0.y, v1, pp);
                pp = fmaf(at0.z, v2, pp);
                pp = fmaf(at0.w, v3, pp);
                pp = fmaf(at1.x, v4, pp);
                pp = fmaf(at1.y, v5, pp);
                pp = fmaf(at1.z, v6, pp);
                pp = fmaf(at1.w, v7, pp);
                pp += __shfl_xor(pp, 1, 64);
                pp += __shfl_xor(pp, 2, 64);
                pp += __shfl_xor(pp, 4, 64);
                pp += __shfl_xor(pp, 8, 64);
                float w = __expf(pp);
                lsum += w;
                acc[0] = fmaf(w, p0.x, acc[0]);
                acc[1] = fmaf(w, p0.y, acc[1]);
                acc[2] = fmaf(w, p1.x, acc[2]);
                acc[3] = fmaf(w, p1.y, acc[3]);
                acc[4] = fmaf(w, p2.x, acc[4]);
                acc[5] = fmaf(w, p2.y, acc[5]);
                acc[6] = fmaf(w, p3.x, acc[6]);
                acc[7] = fmaf(w, p3.y, acc[7]);
            }
        }
    }

    for (int j = beg + 64 + g; j < end; j += 4) {
        int s = (int)col[j];
        uint4 u = *(const uint4*)(basep + (size_t)s * DIM);
        float2 p0 = bf2x(u.x), p1 = bf2x(u.y), p2 = bf2x(u.z), p3 = bf2x(u.w);
        float v0 = p0.x + xr0.x, v1 = p0.y + xr0.y, v2 = p1.x + xr0.z, v3 = p1.y + xr0.w;
        float v4 = p2.x + xr1.x, v5 = p2.y + xr1.y, v6 = p3.x + xr1.z, v7 = p3.y + xr1.w;
        v0 = fmaxf(v0, NEG * v0); v1 = fmaxf(v1, NEG * v1);
        v2 = fmaxf(v2, NEG * v2); v3 = fmaxf(v3, NEG * v3);
        v4 = fmaxf(v4, NEG * v4); v5 = fmaxf(v5, NEG * v5);
        v6 = fmaxf(v6, NEG * v6); v7 = fmaxf(v7, NEG * v7);
        float pp = at0.x * v0;
        pp = fmaf(at0.y, v1, pp);
        pp = fmaf(at0.z, v2, pp);
        pp = fmaf(at0.w, v3, pp);
        pp = fmaf(at1.x, v4, pp);
        pp = fmaf(at1.y, v5, pp);
        pp = fmaf(at1.z, v6, pp);
        pp = fmaf(at1.w, v7, pp);
        pp += __shfl_xor(pp, 1, 64);
        pp += __shfl_xor(pp, 2, 64);
        pp += __shfl_xor(pp, 4, 64);
        pp += __shfl_xor(pp, 8, 64);
        float w = __expf(pp);
        lsum += w;
        acc[0] = fmaf(w, p0.x, acc[0]);
        acc[1] = fmaf(w, p0.y, acc[1]);
        acc[2] = fmaf(w, p1.x, acc[2]);
        acc[3] = fmaf(w, p1.y, acc[3]);
        acc[4] = fmaf(w, p2.x, acc[4]);
        acc[5] = fmaf(w, p2.y, acc[5]);
        acc[6] = fmaf(w, p3.x, acc[6]);
        acc[7] = fmaf(w, p3.y, acc[7]);
    }

#pragma unroll
    for (int i = 0; i < 8; ++i) {
        acc[i] += __shfl_xor(acc[i], 16, 64);
        acc[i] += __shfl_xor(acc[i], 32, 64);
    }
    lsum += __shfl_xor(lsum, 16, 64);
    lsum += __shfl_xor(lsum, 32, 64);

    if (g == 0) {
        float inv = 1.f / fmaxf(lsum, 1e-16f);
        float4 b0 = *(const float4*)(bias + d0);
        float4 b1 = *(const float4*)(bias + d0 + 4);
        float o0 = acc[0] * inv + b0.x;
        float o1 = acc[1] * inv + b0.y;
        float o2 = acc[2] * inv + b0.z;
        float o3 = acc[3] * inv + b0.w;
        float o4 = acc[4] * inv + b1.x;
        float o5 = acc[5] * inv + b1.y;
        float o6 = acc[6] * inv + b1.z;
        float o7 = acc[7] * inv + b1.w;
        if (RELU) {
            o0 = fmaxf(o0, 0.f); o1 = fmaxf(o1, 0.f);
            o2 = fmaxf(o2, 0.f); o3 = fmaxf(o3, 0.f);
            o4 = fmaxf(o4, 0.f); o5 = fmaxf(o5, 0.f);
            o6 = fmaxf(o6, 0.f); o7 = fmaxf(o7, 0.f);
        }
        uint4 o;
        o.x = pk2(o0, o1);
        o.y = pk2(o2, o3);
        o.z = pk2(o4, o5);
        o.w = pk2(o6, o7);
        *(uint4*)(hout + (size_t)node * DIM + d0) = o;
    }
}

// ---------- mean pool (bf16 h) ----------
__global__ void k_mean_part(const u16* __restrict__ hb, float* __restrict__ part) {
    int d = threadIdx.x;
    int b = blockIdx.x;
    int n0 = b * 200;
    float s = 0.f;
    for (int i = 0; i < 200; ++i) {
        union { u32 i; float f; } v;
        v.i = (u32)hb[(size_t)(n0 + i) * DIM + d] << 16;
        s += v.f;
    }
    part[b * DIM + d] = s;
}

__global__ void k_mean_final(const float* __restrict__ part, float* __restrict__ out) {
    int d = threadIdx.x;
    float s = 0.f;
    for (int b = 0; b < 250; ++b) s += part[b * DIM + d];
    out[d] = s * (1.f / (float)N_NODES);
}

// ---------- launch ----------
extern "C" void kernel_launch(void* const* d_in, const int* in_sizes, int n_in,
                              void* d_out, int out_size, void* d_ws, size_t ws_size,
                              hipStream_t stream) {
    int ix, iei, iWl, ibl, iWr, ibr, iatt, ibias;
    if (in_sizes[0] == N_NODES * DIM) {
        ix = 0; iei = 1; iWl = 2; ibl = 3; iWr = 4; ibr = 5; iatt = 6; ibias = 7;
    } else {
        iWl = 0; iWr = 1; iatt = 2; ibias = 3; ibl = 4; ibr = 5; iei = 6; ix = 7;
    }
    const float* x    = (const float*)d_in[ix];
    const void*  ei   = d_in[iei];
    const float* Wl   = (const float*)d_in[iWl];
    const float* bl   = (const float*)d_in[ibl];
    const float* Wr   = (const float*)d_in[iWr];
    const float* br   = (const float*)d_in[ibr];
    const float* att  = (const float*)d_in[iatt];
    const float* bias = (const float*)d_in[ibias];
    float* out = (float*)d_out;

    char* w = (char*)d_ws;
    float* xr = (float*)w;        w += (size_t)N_NODES * DIM * 4;
    float* part = (float*)w;      w += (size_t)256 * DIM * 4;
    uint4* Wtg = (uint4*)w;       w += (size_t)N_LAYERS * 4096 * 16;
    u16* xb  = (u16*)w;           w += (size_t)N_NODES * DIM * 2;
    u16* hb  = (u16*)w;           w += (size_t)N_NODES * DIM * 2;
    u16* xlb = (u16*)w;           w += (size_t)N_NODES * DIM * 2;
    int* row_off = (int*)w;       w += (size_t)(N_NODES + 4) * 4;
    int* flags = (int*)w;         w += 64;
    int* bcnt = (int*)w;          w += (size_t)(NBKT + 4) * 4;
    int* btot = (int*)w;          w += (size_t)(NBKT + 4) * 4;
    int* boff = (int*)w;          w += (size_t)(NBKT + 4) * 4;
    u32* bpk = (u32*)w;           w += (size_t)NBKT * BCAP_A * 4;
    u16* col = (u16*)w;           w += (size_t)(N_EDGES + N_NODES + 64) * 2;

    k_probe<<<1, 256, 0, stream>>>((const int*)ei, flags, bcnt);
    k_cvt_x<<<(N_NODES * DIM / 2 + 255) / 256, 256, 0, stream>>>(x, xb);
    k_cvt_w<<<(N_LAYERS * 4096 + 255) / 256, 256, 0, stream>>>(Wl, Wr, Wtg);
    k_part<<<PBLK, 1024, 0, stream>>>(ei, flags, bcnt, bpk);
    k_deg<<<NBKT, 256, 0, stream>>>(bpk, bcnt, ei, flags, row_off, btot);
    k_bscan<<<1, 256, 0, stream>>>(btot, boff, row_off);
    k_scat<<<NBKT, 256, 0, stream>>>(bpk, bcnt, row_off, boff, btot, col, ei, flags);

    const int mm_grid = (N_NODES + 63) / 64;
    const int edge_grid = (N_NODES * 64 + 255) / 256;

    for (int layer = 0; layer < N_LAYERS; ++layer) {
        const uint4* Wp = Wtg + (size_t)layer * 4096;
        const float* blp = bl + (size_t)layer * DIM;
        const float* brp = br + (size_t)layer * DIM;
        const float* ap  = att + (size_t)layer * DIM;
        const float* bp  = bias + (size_t)layer * DIM;

        const u16* hin = (layer == 0) ? xb : hb;
        k_mm<<<mm_grid, 256, 0, stream>>>(hin, Wp, blp, brp, xlb, xr);

        if (layer < N_LAYERS - 1)
            k_edge<1><<<edge_grid, 256, 0, stream>>>(xlb, xr, row_off, col, ap, bp, hb);
        else
            k_edge<0><<<edge_grid, 256, 0, stream>>>(xlb, xr, row_off, col, ap, bp, hb);
    }

    k_mean_part<<<250, 128, 0, stream>>>(hb, part);
    k_mean_final<<<1, 128, 0, stream>>>(part, out);
}